// Round 7
// baseline (95.492 us; speedup 1.0000x reference)
//
#include <hip/hip_runtime.h>
#include <hip/hip_bf16.h>

typedef __attribute__((ext_vector_type(8))) short short8v;
typedef __attribute__((ext_vector_type(4))) float f32x4;

#define NPW 8               // nodes per wave
#define WPB 4               // waves per 256-thread block
#define WP_ELEMS (9 * 4 * 16 * 8)
#define ROWPTR_OFF 16384    // byte offset of row_ptr inside d_ws

// Setup: (a) pack Wz bf16 table, (b) row_ptr[n] = lower_bound(dst, n), n in [0, N].
// Wz column mapping: k = t*32 + gg*8 + j  <->  c = (gg>>1)*8 + t, i = (gg&1)*8 + j
// (t<8); t==8: be row gg*8+j (gg<2), 0 pad.
__global__ __launch_bounds__(256) void setup_kernel(
    const float* __restrict__ We, const float* __restrict__ be,
    const int* __restrict__ dst,
    unsigned short* __restrict__ wp, int* __restrict__ row_ptr,
    int E, int N) {
  int idx = blockIdx.x * 256 + threadIdx.x;
  if (idx < WP_ELEMS) {
    int j = idx & 7, n = (idx >> 3) & 15, gg = (idx >> 7) & 3, t = idx >> 9;
    float v = 0.f;
    if (t < 8) {
      int c = (gg >> 1) * 8 + t;
      int i = (gg & 1) * 8 + j;
      v = We[c * 256 + i * 16 + n];
    } else if (gg < 2) {
      v = be[(gg * 8 + j) * 16 + n];
    }
    __hip_bfloat16 b = __float2bfloat16(v);
    wp[idx] = __builtin_bit_cast(unsigned short, b);
  }
  if (idx <= N) {
    int lo = 0, hi = E;
    while (lo < hi) {
      int mid = (lo + hi) >> 1;
      if (dst[mid] < idx) lo = mid + 1; else hi = mid;
    }
    row_ptr[idx] = lo;
  }
}

// Node-centric: wave owns nodes [n0, n1), processes edges [row_ptr[n0], row_ptr[n1])
// in 16-edge MFMA tiles, accumulates into private LDS (ds_add_f32), plain stores.
// A-frag: edge = lane&15, K-slice k = g*8+j; Z[k] = ef[(g>>1)*8+t] * h[(g&1)*8+j].
// D: row = edge = base + g*4 + r, col = output feature = lane&15.
__global__ __launch_bounds__(256) void edge_mfma_kernel(
    const float* __restrict__ feat, const float* __restrict__ efeat,
    const float* __restrict__ bias,
    const int* __restrict__ src, const int* __restrict__ dst,
    const unsigned short* __restrict__ wp, const int* __restrict__ row_ptr,
    float* __restrict__ out, int E, int N) {
  __shared__ float lacc[WPB][NPW * 16];
  int wid = threadIdx.x >> 6;
  int lane = threadIdx.x & 63;
  int wave = blockIdx.x * WPB + wid;
  int g = lane >> 4, m = lane & 15;
  int p = g >> 1, hh = g & 1;

  int n0 = wave * NPW;
  if (n0 >= N) return;
  int n1 = min(n0 + NPW, N);

  float* al = lacc[wid];
  al[lane] = 0.f;
  al[lane + 64] = 0.f;

  short8v Bf[9];
#pragma unroll
  for (int t = 0; t < 9; ++t)
    Bf[t] = *reinterpret_cast<const short8v*>(wp + (unsigned)(t * 64 + lane) * 8);

  int estart = row_ptr[n0];
  int eend = row_ptr[n1];

  const float4* ef4 = reinterpret_cast<const float4*>(efeat);
  const float4* f4  = reinterpret_cast<const float4*>(feat);

#pragma unroll 1
  for (int base = estart; base < eend; base += 16) {
    int e = base + m;
    bool valid = e < eend;
    int ec = valid ? e : (eend - 1);
    int s = src[ec];
    float4 E0 = ef4[(unsigned)ec * 4 + p * 2];
    float4 E1 = ef4[(unsigned)ec * 4 + p * 2 + 1];
    float4 H0 = f4[(unsigned)s * 4 + hh * 2];
    float4 H1 = f4[(unsigned)s * 4 + hh * 2 + 1];
    if (!valid) {  // zero BOTH ef and h: kills Z products AND the be-passthrough row
      E0 = make_float4(0.f, 0.f, 0.f, 0.f); E1 = E0; H0 = E0; H1 = E0;
    }

    // node slots for this lane's 4 output rows (edges base + g*4 + r)
    int eb = base + g * 4;
    int q0 = dst[min(eb + 0, eend - 1)] - n0;
    int q1 = dst[min(eb + 1, eend - 1)] - n0;
    int q2 = dst[min(eb + 2, eend - 1)] - n0;
    int q3 = dst[min(eb + 3, eend - 1)] - n0;

    float efs[8] = {E0.x, E0.y, E0.z, E0.w, E1.x, E1.y, E1.z, E1.w};
    float h[8]   = {H0.x, H0.y, H0.z, H0.w, H1.x, H1.y, H1.z, H1.w};

    f32x4 acc = {0.f, 0.f, 0.f, 0.f};
#pragma unroll
    for (int t = 0; t < 8; ++t) {
      short8v A;
#pragma unroll
      for (int jj = 0; jj < 8; ++jj) {
        float prod = efs[t] * h[jj];               // fp32 product, single rounding
        __hip_bfloat16 bb = __float2bfloat16(prod);
        A[jj] = __builtin_bit_cast(short, bb);
      }
      acc = __builtin_amdgcn_mfma_f32_16x16x32_bf16(A, Bf[t], acc, 0, 0, 0);
    }
    {  // be passthrough K-tile (Z = h[i] at k=256+i), zero pad k>=272
      short8v A;
#pragma unroll
      for (int jj = 0; jj < 8; ++jj) {
        float hv = (g < 2) ? h[jj] : 0.f;
        __hip_bfloat16 bb = __float2bfloat16(hv);
        A[jj] = __builtin_bit_cast(short, bb);
      }
      acc = __builtin_amdgcn_mfma_f32_16x16x32_bf16(A, Bf[8], acc, 0, 0, 0);
    }

    // LDS accumulation: ds_add_f32, no L2 round-trip, no same-line L2 serialization
    atomicAdd(&al[q0 * 16 + m], acc[0]);
    atomicAdd(&al[q1 * 16 + m], acc[1]);
    atomicAdd(&al[q2 * 16 + m], acc[2]);
    atomicAdd(&al[q3 * 16 + m], acc[3]);
  }

  __threadfence_block();  // drain ds_adds before reading (same-wave DS is in-order; belt&braces)

  int nn = n1 - n0;
#pragma unroll
  for (int r = 0; r < 2; ++r) {
    int v = lane + r * 64;
    int q = v >> 4, c = v & 15;
    if (q < nn) {
      int gi = (n0 + q) * 16 + c;
      out[gi] = al[v] + feat[gi] + bias[c];  // residual + bias fused; plain store
    }
  }
}

extern "C" void kernel_launch(void* const* d_in, const int* in_sizes, int n_in,
                              void* d_out, int out_size, void* d_ws, size_t ws_size,
                              hipStream_t stream) {
  const float* feat  = (const float*)d_in[0];
  const float* efeat = (const float*)d_in[1];
  const float* We    = (const float*)d_in[2];
  const float* be    = (const float*)d_in[3];
  const float* bias  = (const float*)d_in[4];
  const int*   src   = (const int*)d_in[5];
  const int*   dst   = (const int*)d_in[6];
  float* out = (float*)d_out;

  int E = in_sizes[5];
  int N = out_size / 16;  // 50000 nodes

  unsigned short* wp = (unsigned short*)d_ws;
  int* row_ptr = (int*)((char*)d_ws + ROWPTR_OFF);

  int setup_items = (N + 1) > WP_ELEMS ? (N + 1) : WP_ELEMS;
  setup_kernel<<<(setup_items + 255) / 256, 256, 0, stream>>>(We, be, dst, wp, row_ptr, E, N);

  int waves = (N + NPW - 1) / NPW;
  int blocks = (waves + WPB - 1) / WPB;
  edge_mfma_kernel<<<blocks, 256, 0, stream>>>(feat, efeat, bias, src, dst,
                                               wp, row_ptr, out, E, N);
}

// Round 8
// 49.927 us; speedup vs baseline: 1.9126x; 1.9126x over previous
//
#include <hip/hip_runtime.h>
#include <hip/hip_bf16.h>

typedef __attribute__((ext_vector_type(2))) _Float16 half2v;
typedef __attribute__((ext_vector_type(8))) _Float16 half8v;
typedef __attribute__((ext_vector_type(4))) float f32x4;

#define NBLK 2048
#define WT (NBLK * 4)  // total waves (4 waves / 256-thread block)

// Fused: out = feat + bias (blocks [0,initB)), Wz f16 pack (blocks [initB, ...))
// Wz column mapping (K-permutation): k = t*32 + gg*8 + j  <->  c = (gg>>1)*8 + t,
// i = (gg&1)*8 + j  (t<8);  t==8: k=256+gg*8+j -> be row gg*8+j (gg<2), 0 pad.
__global__ __launch_bounds__(256) void setup_kernel(
    const float* __restrict__ feat, const float* __restrict__ bias,
    const float* __restrict__ We, const float* __restrict__ be,
    float* __restrict__ out, unsigned short* __restrict__ wp,
    int n_elems, int initB) {
  if ((int)blockIdx.x < initB) {
    int g = blockIdx.x * 256 + threadIdx.x;
    int base = g * 4;
    if (base < n_elems) {
      float4 f = *reinterpret_cast<const float4*>(feat + base);
      const float4* b4 = reinterpret_cast<const float4*>(bias);
      float4 b = b4[g & 3];
      float4 o;
      o.x = f.x + b.x; o.y = f.y + b.y; o.z = f.z + b.z; o.w = f.w + b.w;
      *reinterpret_cast<float4*>(out + base) = o;
    }
  } else {
    int idx = (blockIdx.x - initB) * 256 + threadIdx.x;
    if (idx < 9 * 4 * 16 * 8) {
      int j = idx & 7, n = (idx >> 3) & 15, gg = (idx >> 7) & 3, t = idx >> 9;
      float v = 0.f;
      if (t < 8) {
        int c = (gg >> 1) * 8 + t;
        int i = (gg & 1) * 8 + j;
        v = We[c * 256 + i * 16 + n];
      } else if (gg < 2) {
        v = be[(gg * 8 + j) * 16 + n];
      }
      _Float16 hv = (_Float16)v;
      wp[idx] = __builtin_bit_cast(unsigned short, hv);
    }
  }
}

// A-frag: edge m=lane&15, K-slice k=g*8+j; Z[k] = ef[(g>>1)*8+t] * h[(g&1)*8+j]
// B-frag Bf[t]: lane reads wp[(t*64+lane)*8] (contiguous). D: col=m, row=g*4+r.
// Two independent accumulator chains (even t / odd t + be-tile), summed at end.
__device__ __forceinline__ void compute_tile(
    float4 E0, float4 E1, float4 H0, float4 H1, int4 dd,
    int g, int m, const half8v* Bf, float* __restrict__ out) {
  // convert staged f32 -> packed f16 (v_cvt_pkrtz_f16_f32)
  half2v ef2[4], h2[4];
  ef2[0] = half2v{(_Float16)E0.x, (_Float16)E0.y};
  ef2[1] = half2v{(_Float16)E0.z, (_Float16)E0.w};
  ef2[2] = half2v{(_Float16)E1.x, (_Float16)E1.y};
  ef2[3] = half2v{(_Float16)E1.z, (_Float16)E1.w};
  h2[0]  = half2v{(_Float16)H0.x, (_Float16)H0.y};
  h2[1]  = half2v{(_Float16)H0.z, (_Float16)H0.w};
  h2[2]  = half2v{(_Float16)H1.x, (_Float16)H1.y};
  h2[3]  = half2v{(_Float16)H1.z, (_Float16)H1.w};

  f32x4 accA = {0.f, 0.f, 0.f, 0.f};
  f32x4 accB = {0.f, 0.f, 0.f, 0.f};
#pragma unroll
  for (int t = 0; t < 8; ++t) {
    _Float16 ev = ef2[t >> 1][t & 1];
    half2v evb = half2v{ev, ev};
    half2v a0 = evb * h2[0], a1 = evb * h2[1], a2 = evb * h2[2], a3 = evb * h2[3];
    half8v A;
    A[0] = a0[0]; A[1] = a0[1]; A[2] = a1[0]; A[3] = a1[1];
    A[4] = a2[0]; A[5] = a2[1]; A[6] = a3[0]; A[7] = a3[1];
    if (t & 1)
      accB = __builtin_amdgcn_mfma_f32_16x16x32_f16(A, Bf[t], accB, 0, 0, 0);
    else
      accA = __builtin_amdgcn_mfma_f32_16x16x32_f16(A, Bf[t], accA, 0, 0, 0);
  }
  {  // be passthrough K-tile (Z = h[i] at k=256+i), zero pad k>=272
    half2v z = half2v{(_Float16)0.f, (_Float16)0.f};
    half2v b0 = (g < 2) ? h2[0] : z, b1 = (g < 2) ? h2[1] : z;
    half2v b2 = (g < 2) ? h2[2] : z, b3 = (g < 2) ? h2[3] : z;
    half8v A;
    A[0] = b0[0]; A[1] = b0[1]; A[2] = b1[0]; A[3] = b1[1];
    A[4] = b2[0]; A[5] = b2[1]; A[6] = b3[0]; A[7] = b3[1];
    accB = __builtin_amdgcn_mfma_f32_16x16x32_f16(A, Bf[8], accB, 0, 0, 0);
  }
  f32x4 acc;
  acc[0] = accA[0] + accB[0]; acc[1] = accA[1] + accB[1];
  acc[2] = accA[2] + accB[2]; acc[3] = accA[3] + accB[3];

  // dst sorted -> run-combine then one atomic per run
  float run = acc[0];
  int cur = dd.x;
  if (dd.y == cur) run += acc[1];
  else { unsafeAtomicAdd(out + (size_t)cur * 16 + m, run); cur = dd.y; run = acc[1]; }
  if (dd.z == cur) run += acc[2];
  else { unsafeAtomicAdd(out + (size_t)cur * 16 + m, run); cur = dd.z; run = acc[2]; }
  if (dd.w == cur) run += acc[3];
  else { unsafeAtomicAdd(out + (size_t)cur * 16 + m, run); cur = dd.w; run = acc[3]; }
  unsafeAtomicAdd(out + (size_t)cur * 16 + m, run);
}

__global__ __launch_bounds__(256) void edge_mfma_kernel(
    const float* __restrict__ feat, const float* __restrict__ efeat,
    const int* __restrict__ src, const int* __restrict__ dst,
    const unsigned short* __restrict__ wp,
    float* __restrict__ out, int E) {
  int wave = blockIdx.x * 4 + (threadIdx.x >> 6);
  int lane = threadIdx.x & 63;
  int g = lane >> 4;
  int m = lane & 15;
  int p = g >> 1;        // ef slice
  int hh = g & 1;        // h slice selector

  int ntiles = (E + 15) >> 4;
  if (wave >= ntiles) return;
  const bool partialF = (E & 15) != 0;
  const int lastT = ntiles - 1;

  half8v Bf[9];
#pragma unroll
  for (int t = 0; t < 9; ++t)
    Bf[t] = *reinterpret_cast<const half8v*>(wp + (unsigned)(t * 64 + lane) * 8);

  const float4* ef4 = reinterpret_cast<const float4*>(efeat);
  const float4* f4  = reinterpret_cast<const float4*>(feat);
  const int4*   d4  = reinterpret_cast<const int4*>(dst);

  // ---- prologue: load current tile fully ----
  int tile = wave;
  float4 E0, E1, H0, H1;
  int4 dd;
  if (__builtin_expect(partialF && tile == lastT, 0)) {
    int e = tile * 16 + m;
    int ec = min(e, E - 1);
    E0 = ef4[(unsigned)ec * 4 + p * 2]; E1 = ef4[(unsigned)ec * 4 + p * 2 + 1];
    if (e >= E) { E0 = make_float4(0.f,0.f,0.f,0.f); E1 = E0; }
    int s = src[ec];
    H0 = f4[(unsigned)s * 4 + hh * 2]; H1 = f4[(unsigned)s * 4 + hh * 2 + 1];
    if (e >= E) { H0 = make_float4(0.f,0.f,0.f,0.f); H1 = H0; }
    int b = tile * 16 + g * 4;
    dd.x = dst[min(b + 0, E - 1)]; dd.y = dst[min(b + 1, E - 1)];
    dd.z = dst[min(b + 2, E - 1)]; dd.w = dst[min(b + 3, E - 1)];
  } else {
    int e = tile * 16 + m;
    int s = src[e];
    E0 = ef4[(unsigned)e * 4 + p * 2]; E1 = ef4[(unsigned)e * 4 + p * 2 + 1];
    dd = d4[(unsigned)tile * 4 + g];
    H0 = f4[(unsigned)s * 4 + hh * 2]; H1 = f4[(unsigned)s * 4 + hh * 2 + 1];
  }

  int tile1 = tile + WT;
  int s1 = 0;
  if (tile1 < ntiles) s1 = src[min(tile1 * 16 + m, E - 1)];

  // ---- steady state: prefetch payload n+1 & src n+2, then compute n ----
  while (tile1 < ntiles) {
    int tile2 = tile1 + WT;

    float4 E0n, E1n, H0n, H1n;
    int4 ddn;
    if (__builtin_expect(partialF && tile1 == lastT, 0)) {
      int e = tile1 * 16 + m;
      int ec = min(e, E - 1);
      E0n = ef4[(unsigned)ec * 4 + p * 2]; E1n = ef4[(unsigned)ec * 4 + p * 2 + 1];
      if (e >= E) { E0n = make_float4(0.f,0.f,0.f,0.f); E1n = E0n; }
      int b = tile1 * 16 + g * 4;
      ddn.x = dst[min(b + 0, E - 1)]; ddn.y = dst[min(b + 1, E - 1)];
      ddn.z = dst[min(b + 2, E - 1)]; ddn.w = dst[min(b + 3, E - 1)];
    } else {
      int e = tile1 * 16 + m;
      E0n = ef4[(unsigned)e * 4 + p * 2]; E1n = ef4[(unsigned)e * 4 + p * 2 + 1];
      ddn = d4[(unsigned)tile1 * 4 + g];
    }
    // gather for tile1 — s1 loaded a full iteration ago, its wait is free
    H0n = f4[(unsigned)s1 * 4 + hh * 2]; H1n = f4[(unsigned)s1 * 4 + hh * 2 + 1];
    // src for tile2 (clamped; unused if loop exits)
    int s2 = src[min(tile2 * 16 + m, E - 1)];

    __builtin_amdgcn_sched_barrier(0);  // pin: all prefetch issued before compute

    compute_tile(E0, E1, H0, H1, dd, g, m, Bf, out);

    E0 = E0n; E1 = E1n; H0 = H0n; H1 = H1n; dd = ddn; s1 = s2;
    tile = tile1; tile1 = tile2;
  }

  // tail-tile h zeroing for masked lanes is handled in the partialF branches
  compute_tile(E0, E1, H0, H1, dd, g, m, Bf, out);
}

extern "C" void kernel_launch(void* const* d_in, const int* in_sizes, int n_in,
                              void* d_out, int out_size, void* d_ws, size_t ws_size,
                              hipStream_t stream) {
  const float* feat  = (const float*)d_in[0];
  const float* efeat = (const float*)d_in[1];
  const float* We    = (const float*)d_in[2];
  const float* be    = (const float*)d_in[3];
  const float* bias  = (const float*)d_in[4];
  const int*   src   = (const int*)d_in[5];
  const int*   dst   = (const int*)d_in[6];
  float* out = (float*)d_out;

  int E = in_sizes[5];
  int n_elems = out_size;  // 50000*16

  int groups = (n_elems + 3) / 4;
  int initB = (groups + 255) / 256;
  int prepB = (9 * 4 * 16 * 8 + 255) / 256;
  setup_kernel<<<initB + prepB, 256, 0, stream>>>(feat, bias, We, be, out,
                                                  (unsigned short*)d_ws, n_elems, initB);

  int ntiles = (E + 15) / 16;
  int blocks = min(NBLK, (ntiles + 3) / 4);
  edge_mfma_kernel<<<blocks, 256, 0, stream>>>(feat, efeat, src, dst,
                                               (const unsigned short*)d_ws, out, E);
}

// Round 9
// 47.483 us; speedup vs baseline: 2.0111x; 1.0515x over previous
//
#include <hip/hip_runtime.h>
#include <hip/hip_bf16.h>

typedef __attribute__((ext_vector_type(2))) _Float16 half2v;
typedef __attribute__((ext_vector_type(8))) _Float16 half8v;
typedef __attribute__((ext_vector_type(4))) float f32x4;

#define NBLK 2048   // must be a multiple of 8 (XCD chunking)

// Fused: out = feat + bias (blocks [0,initB)), Wz f16 pack (blocks [initB, ...))
// Wz column mapping (K-permutation): k = t*32 + gg*8 + j  <->  c = (gg>>1)*8 + t,
// i = (gg&1)*8 + j  (t<8);  t==8: k=256+gg*8+j -> be row gg*8+j (gg<2), 0 pad.
__global__ __launch_bounds__(256) void setup_kernel(
    const float* __restrict__ feat, const float* __restrict__ bias,
    const float* __restrict__ We, const float* __restrict__ be,
    float* __restrict__ out, unsigned short* __restrict__ wp,
    int n_elems, int initB) {
  if ((int)blockIdx.x < initB) {
    int g = blockIdx.x * 256 + threadIdx.x;
    int base = g * 4;
    if (base < n_elems) {
      float4 f = *reinterpret_cast<const float4*>(feat + base);
      const float4* b4 = reinterpret_cast<const float4*>(bias);
      float4 b = b4[g & 3];
      float4 o;
      o.x = f.x + b.x; o.y = f.y + b.y; o.z = f.z + b.z; o.w = f.w + b.w;
      *reinterpret_cast<float4*>(out + base) = o;
    }
  } else {
    int idx = (blockIdx.x - initB) * 256 + threadIdx.x;
    if (idx < 9 * 4 * 16 * 8) {
      int j = idx & 7, n = (idx >> 3) & 15, gg = (idx >> 7) & 3, t = idx >> 9;
      float v = 0.f;
      if (t < 8) {
        int c = (gg >> 1) * 8 + t;
        int i = (gg & 1) * 8 + j;
        v = We[c * 256 + i * 16 + n];
      } else if (gg < 2) {
        v = be[(gg * 8 + j) * 16 + n];
      }
      _Float16 hv = (_Float16)v;
      wp[idx] = __builtin_bit_cast(unsigned short, hv);
    }
  }
}

// A-frag: edge m=lane&15, K-slice k=g*8+j; Z[k] = ef[(g>>1)*8+t] * h[(g&1)*8+j]
// B-frag Bf[t]: lane reads wp[(t*64+lane)*8]. D: col=m, row=g*4+r.
__device__ __forceinline__ void compute_tile(
    float4 E0, float4 E1, float4 H0, float4 H1, int4 dd,
    int g, int m, const half8v* Bf, float* __restrict__ out) {
  half2v ef2[4], h2[4];
  ef2[0] = half2v{(_Float16)E0.x, (_Float16)E0.y};
  ef2[1] = half2v{(_Float16)E0.z, (_Float16)E0.w};
  ef2[2] = half2v{(_Float16)E1.x, (_Float16)E1.y};
  ef2[3] = half2v{(_Float16)E1.z, (_Float16)E1.w};
  h2[0]  = half2v{(_Float16)H0.x, (_Float16)H0.y};
  h2[1]  = half2v{(_Float16)H0.z, (_Float16)H0.w};
  h2[2]  = half2v{(_Float16)H1.x, (_Float16)H1.y};
  h2[3]  = half2v{(_Float16)H1.z, (_Float16)H1.w};

  f32x4 accA = {0.f, 0.f, 0.f, 0.f};
  f32x4 accB = {0.f, 0.f, 0.f, 0.f};
#pragma unroll
  for (int t = 0; t < 8; ++t) {
    _Float16 ev = ef2[t >> 1][t & 1];
    half2v evb = half2v{ev, ev};
    half2v a0 = evb * h2[0], a1 = evb * h2[1], a2 = evb * h2[2], a3 = evb * h2[3];
    half8v A;
    A[0] = a0[0]; A[1] = a0[1]; A[2] = a1[0]; A[3] = a1[1];
    A[4] = a2[0]; A[5] = a2[1]; A[6] = a3[0]; A[7] = a3[1];
    if (t & 1)
      accB = __builtin_amdgcn_mfma_f32_16x16x32_f16(A, Bf[t], accB, 0, 0, 0);
    else
      accA = __builtin_amdgcn_mfma_f32_16x16x32_f16(A, Bf[t], accA, 0, 0, 0);
  }
  {  // be passthrough K-tile (Z = h[i] at k=256+i), zero pad k>=272
    half2v z = half2v{(_Float16)0.f, (_Float16)0.f};
    half2v b0 = (g < 2) ? h2[0] : z, b1 = (g < 2) ? h2[1] : z;
    half2v b2 = (g < 2) ? h2[2] : z, b3 = (g < 2) ? h2[3] : z;
    half8v A;
    A[0] = b0[0]; A[1] = b0[1]; A[2] = b1[0]; A[3] = b1[1];
    A[4] = b2[0]; A[5] = b2[1]; A[6] = b3[0]; A[7] = b3[1];
    accB = __builtin_amdgcn_mfma_f32_16x16x32_f16(A, Bf[8], accB, 0, 0, 0);
  }
  f32x4 acc;
  acc[0] = accA[0] + accB[0]; acc[1] = accA[1] + accB[1];
  acc[2] = accA[2] + accB[2]; acc[3] = accA[3] + accB[3];

  // ---- fast path: whole 16-edge tile has a single dst (sorted => endpoints equal) ----
  int nA = __shfl(dd.x, 0, 64);
  int nB = __shfl(dd.w, 48, 64);
  if (nA == nB) {
    float v = acc[0] + acc[1] + acc[2] + acc[3];
    v += __shfl_xor(v, 32, 64);
    v += __shfl_xor(v, 16, 64);
    if (g == 0) unsafeAtomicAdd(out + (size_t)nA * 16 + m, v);
    return;
  }

  // ---- general path: per-group run-combine, one atomic per run ----
  float run = acc[0];
  int cur = dd.x;
  if (dd.y == cur) run += acc[1];
  else { unsafeAtomicAdd(out + (size_t)cur * 16 + m, run); cur = dd.y; run = acc[1]; }
  if (dd.z == cur) run += acc[2];
  else { unsafeAtomicAdd(out + (size_t)cur * 16 + m, run); cur = dd.z; run = acc[2]; }
  if (dd.w == cur) run += acc[3];
  else { unsafeAtomicAdd(out + (size_t)cur * 16 + m, run); cur = dd.w; run = acc[3]; }
  unsafeAtomicAdd(out + (size_t)cur * 16 + m, run);
}

// XCD-chunked persistent waves: blocks with (bid&7)==x process the x-th contiguous
// 1/8 of the tile list. dst sorted => each out line is RMW'd by one XCD only.
__global__ __launch_bounds__(256) void edge_mfma_kernel(
    const float* __restrict__ feat, const float* __restrict__ efeat,
    const int* __restrict__ src, const int* __restrict__ dst,
    const unsigned short* __restrict__ wp,
    float* __restrict__ out, int E) {
  int wid = threadIdx.x >> 6;
  int lane = threadIdx.x & 63;
  int g = lane >> 4;
  int m = lane & 15;
  int p = g >> 1;        // ef slice
  int hh = g & 1;        // h slice selector

  int ntiles = (E + 15) >> 4;
  const bool partialF = (E & 15) != 0;
  const int lastT = ntiles - 1;

  int T8 = (ntiles + 7) >> 3;
  int xcd = blockIdx.x & 7;
  int wic = (blockIdx.x >> 3) * 4 + wid;   // wave index within chunk
  int CW = (gridDim.x >> 3) * 4;           // waves per chunk
  int cs = xcd * T8;
  int ce = min(cs + T8, ntiles);

  int tile = cs + wic;
  if (tile >= ce) return;

  half8v Bf[9];
#pragma unroll
  for (int t = 0; t < 9; ++t)
    Bf[t] = *reinterpret_cast<const half8v*>(wp + (unsigned)(t * 64 + lane) * 8);

  const float4* ef4 = reinterpret_cast<const float4*>(efeat);
  const float4* f4  = reinterpret_cast<const float4*>(feat);
  const int4*   d4  = reinterpret_cast<const int4*>(dst);

  // ---- prologue: load current tile fully ----
  float4 E0, E1, H0, H1;
  int4 dd;
  if (__builtin_expect(partialF && tile == lastT, 0)) {
    int e = tile * 16 + m;
    int ec = min(e, E - 1);
    E0 = ef4[(unsigned)ec * 4 + p * 2]; E1 = ef4[(unsigned)ec * 4 + p * 2 + 1];
    if (e >= E) { E0 = make_float4(0.f,0.f,0.f,0.f); E1 = E0; }
    int s = src[ec];
    H0 = f4[(unsigned)s * 4 + hh * 2]; H1 = f4[(unsigned)s * 4 + hh * 2 + 1];
    if (e >= E) { H0 = make_float4(0.f,0.f,0.f,0.f); H1 = H0; }
    int b = tile * 16 + g * 4;
    dd.x = dst[min(b + 0, E - 1)]; dd.y = dst[min(b + 1, E - 1)];
    dd.z = dst[min(b + 2, E - 1)]; dd.w = dst[min(b + 3, E - 1)];
  } else {
    int e = tile * 16 + m;
    int s = src[e];
    E0 = ef4[(unsigned)e * 4 + p * 2]; E1 = ef4[(unsigned)e * 4 + p * 2 + 1];
    dd = d4[(unsigned)tile * 4 + g];
    H0 = f4[(unsigned)s * 4 + hh * 2]; H1 = f4[(unsigned)s * 4 + hh * 2 + 1];
  }

  int tile1 = tile + CW;
  int s1 = 0;
  if (tile1 < ce) s1 = src[min(tile1 * 16 + m, E - 1)];

  // ---- steady state: prefetch payload n+1 & src n+2, then compute n ----
  while (tile1 < ce) {
    int tile2 = tile1 + CW;

    float4 E0n, E1n, H0n, H1n;
    int4 ddn;
    if (__builtin_expect(partialF && tile1 == lastT, 0)) {
      int e = tile1 * 16 + m;
      int ec = min(e, E - 1);
      E0n = ef4[(unsigned)ec * 4 + p * 2]; E1n = ef4[(unsigned)ec * 4 + p * 2 + 1];
      if (e >= E) { E0n = make_float4(0.f,0.f,0.f,0.f); E1n = E0n; }
      int b = tile1 * 16 + g * 4;
      ddn.x = dst[min(b + 0, E - 1)]; ddn.y = dst[min(b + 1, E - 1)];
      ddn.z = dst[min(b + 2, E - 1)]; ddn.w = dst[min(b + 3, E - 1)];
    } else {
      int e = tile1 * 16 + m;
      E0n = ef4[(unsigned)e * 4 + p * 2]; E1n = ef4[(unsigned)e * 4 + p * 2 + 1];
      ddn = d4[(unsigned)tile1 * 4 + g];
    }
    // gather for tile1 — s1 loaded a full iteration ago, its wait is free
    H0n = f4[(unsigned)s1 * 4 + hh * 2]; H1n = f4[(unsigned)s1 * 4 + hh * 2 + 1];
    // src for tile2 (clamped; unused if loop exits)
    int s2 = src[min(tile2 * 16 + m, E - 1)];

    __builtin_amdgcn_sched_barrier(0);  // pin: all prefetch issued before compute

    compute_tile(E0, E1, H0, H1, dd, g, m, Bf, out);

    E0 = E0n; E1 = E1n; H0 = H0n; H1 = H1n; dd = ddn; s1 = s2;
    tile = tile1; tile1 = tile2;
  }

  compute_tile(E0, E1, H0, H1, dd, g, m, Bf, out);
}

extern "C" void kernel_launch(void* const* d_in, const int* in_sizes, int n_in,
                              void* d_out, int out_size, void* d_ws, size_t ws_size,
                              hipStream_t stream) {
  const float* feat  = (const float*)d_in[0];
  const float* efeat = (const float*)d_in[1];
  const float* We    = (const float*)d_in[2];
  const float* be    = (const float*)d_in[3];
  const float* bias  = (const float*)d_in[4];
  const int*   src   = (const int*)d_in[5];
  const int*   dst   = (const int*)d_in[6];
  float* out = (float*)d_out;

  int E = in_sizes[5];
  int n_elems = out_size;  // 50000*16

  int groups = (n_elems + 3) / 4;
  int initB = (groups + 255) / 256;
  int prepB = (9 * 4 * 16 * 8 + 255) / 256;
  setup_kernel<<<initB + prepB, 256, 0, stream>>>(feat, bias, We, be, out,
                                                  (unsigned short*)d_ws, n_elems, initB);

  // Fixed multiple-of-8 grid; per-chunk grid-stride loops absorb any E.
  edge_mfma_kernel<<<NBLK, 256, 0, stream>>>(feat, efeat, src, dst,
                                             (const unsigned short*)d_ws, out, E);
}